// Round 6
// baseline (31.641 us; speedup 1.0000x reference)
//
#include <hip/hip_runtime.h>
#include <cstdint>

typedef unsigned short u16;
typedef unsigned int u32;
typedef unsigned short us2 __attribute__((ext_vector_type(2)));

constexpr int BB = 16, HH = 512, WW = 512;
constexpr int NPIX = BB * HH * WW;          // 4,194,304

// workspace layout (bytes)
constexpr size_t D1_OFF   = 0;                    // s8 signed d1 (cap 127), 4 MiB
constexpr size_t PART_OFF = (size_t)NPIX;

// envelope tiling
constexpr int HALO  = 32;                 // vertical halo (deep search cap)
constexpr int XT    = 64;                 // output rows per block
constexpr int TROWS = XT + 2 * HALO;      // 128 tile rows
constexpr int CDW   = TROWS / 2 + 1;      // 65 dwords per padded LDS column

// ---------------- Kernel A: per-row 1D distances (single boundary scan) ------
// d1 = distance to nearest opposite-value pixel in the row (= distance to the
// nearest run boundary), capped at 127. v = t ? +d1 : -d1 stored as s8.
__global__ void __launch_bounds__(256) k_rows(const int* __restrict__ tg,
                                              char* __restrict__ d1b) {
  const int lane = threadIdx.x & 63;
  const int wv   = threadIdx.x >> 6;
  const int row  = blockIdx.x * 4 + wv;        // b*512 + h, 8192 rows
  const int c0   = lane * 8;
  const int* rp  = tg + (size_t)row * WW;
  int4 va = *(const int4*)(rp + c0);
  int4 vb = *(const int4*)(rp + c0 + 4);
  int t[8] = {va.x, va.y, va.z, va.w, vb.x, vb.y, vb.z, vb.w};
  int tprev0 = __shfl_up(t[7], 1);   // lane0 value unused (i==0 case)
  int tnext7 = __shfl_down(t[0], 1); // lane63 value unused (i==511 case)

  // left boundary positions, inclusive prefix max
  int lm[8]; int m = -2048;
  #pragma unroll
  for (int k = 0; k < 8; ++k) {
    int i = c0 + k;
    int tp = (k == 0) ? tprev0 : t[k - 1];
    int c = (i > 0 && t[k] != tp) ? i : -2048;
    m = max(m, c); lm[k] = m;
  }
  int X = m;
  #pragma unroll
  for (int off = 1; off < 64; off <<= 1) {
    int y = __shfl_up(X, off);
    if (lane >= off) X = max(X, y);
  }
  int E = __shfl_up(X, 1); if (lane == 0) E = -2048;

  // right boundary positions, inclusive suffix min
  int sm[8]; m = 2559;
  #pragma unroll
  for (int k = 7; k >= 0; --k) {
    int i = c0 + k;
    int tn = (k == 7) ? tnext7 : t[k + 1];
    int c = (i < 511 && t[k] != tn) ? i : 2559;
    m = min(m, c); sm[k] = m;
  }
  int X2 = m;
  #pragma unroll
  for (int off = 1; off < 64; off <<= 1) {
    int y = __shfl_down(X2, off);
    if (lane + off < 64) X2 = min(X2, y);
  }
  int E2 = __shfl_down(X2, 1); if (lane == 63) E2 = 2559;

  u32 lo = 0, hi = 0;
  #pragma unroll
  for (int k = 0; k < 8; ++k) {
    int i = c0 + k;
    int L = max(lm[k], E), R = min(sm[k], E2);
    int d1 = min(min(i - L + 1, R - i + 1), 127);
    int v = t[k] ? d1 : -d1;
    u32 b8 = (u32)(v & 0xff);
    if (k < 4) lo |= b8 << (8 * k); else hi |= b8 << (8 * (k - 4));
  }
  uint2 o = make_uint2(lo, hi);
  ((uint2*)d1b)[(size_t)row * (WW / 8) + lane] = o;
}

// ------------- Kernel B: column lower-envelope + all reductions --------------
// Single LDS tile of packed bytes: u16 = pos8 | neg8<<8 per pixel (one byte is
// always 0; cap 127), u32 = two consecutive rows. A thread's 8 row-pairs share
// a 9-dword register sliding window (9 init reads + 7 slides). Class
// extraction via packed per-half shift (0/8) + mask; dy^2 are packed
// compile-time constants. Sentinel 0x7f7f pads OOB rows.
__global__ void __launch_bounds__(256) k_env(const char* __restrict__ d1b,
                                             const float* __restrict__ inp,
                                             float* __restrict__ partS,
                                             u32* __restrict__ partM,
                                             float* __restrict__ partP,
                                             float* __restrict__ partTP,
                                             int* __restrict__ partT) {
  __shared__ u32 combT[64 * CDW];              // column-major, 2 rows per dword
  const int tid = threadIdx.x;
  const int cg = blockIdx.x, xt = blockIdx.y, b = blockIdx.z;
  const int w0 = cg * 64, x0 = xt * XT;

  // transposed staging: 512 units = (row-pair r2) x (col-group c8)
  #pragma unroll
  for (int u = 0; u < 2; ++u) {
    int idx = tid + u * 256;
    int r2 = idx >> 3, c8 = idx & 7;
    int g0 = x0 - HALO + 2 * r2;
    const char* base = d1b + ((size_t)(b * HH)) * WW + w0 + c8 * 8;
    uint2 A = make_uint2(0, 0), Bv = make_uint2(0, 0);
    bool ok0 = (unsigned)g0 < (unsigned)HH;
    bool ok1 = (unsigned)(g0 + 1) < (unsigned)HH;
    if (ok0) A  = *(const uint2*)(base + (size_t)g0 * WW);
    if (ok1) Bv = *(const uint2*)(base + (size_t)(g0 + 1) * WW);
    u32 aw[2] = {A.x, A.y}, bw[2] = {Bv.x, Bv.y};
    #pragma unroll
    for (int j = 0; j < 8; ++j) {
      int sa = ((int)(aw[j >> 2] << ((3 - (j & 3)) * 8))) >> 24;  // sext byte
      int sb = ((int)(bw[j >> 2] << ((3 - (j & 3)) * 8))) >> 24;
      u32 ua = ok0 ? (sa >= 0 ? (u32)sa : (((u32)(-sa)) << 8)) : 0x7f7fu;
      u32 ub = ok1 ? (sb >= 0 ? (u32)sb : (((u32)(-sb)) << 8)) : 0x7f7fu;
      combT[(c8 * 8 + j) * CDW + r2] = ua | (ub << 16);
    }
  }
  __syncthreads();

  // packed dy^2 constants: KP0 for even own row, KP1 for odd own row
  constexpr u32 KP0[9] = {64 | (49u << 16), 36 | (25u << 16), 16 | (9u << 16),
                          4 | (1u << 16),  0 | (1u << 16),  4 | (9u << 16),
                          16 | (25u << 16), 36 | (49u << 16), 64 | (81u << 16)};
  constexpr u32 KP1[9] = {81 | (64u << 16), 49 | (36u << 16), 25 | (16u << 16),
                          9 | (4u << 16),  1 | (0u << 16),  1 | (4u << 16),
                          9 | (16u << 16), 25 | (36u << 16), 49 | (64u << 16)};

  const int wv = tid >> 6, lane = tid & 63;
  const int E0 = (HALO + wv * 16) / 2;         // first own row-pair dword
  const u32* colp = combT + lane * CDW;
  const float* ip0 = inp + ((size_t)(b * HH + x0 + wv * 16)) * WW + w0 + lane;
  float aP = 0.f, aTP = 0.f, aS = 0.f;
  u32 aM = 0; int aC = 0;

  u32 w[9];
  #pragma unroll
  for (int j = 0; j < 9; ++j) w[j] = colp[E0 - 4 + j];

  #pragma unroll
  for (int k2 = 0; k2 < 8; ++k2) {
    const u32 O = w[4];                        // own pair dword
    const u32 o0 = O & 0xffffu, o1 = O >> 16;
    const int uo0 = (int)((o0 | (o0 >> 8)) & 0xffu);
    const int uo1 = (int)((o1 | (o1 >> 8)) & 0xffu);
    const bool fg0 = (o0 & 0xffu) != 0;
    const bool fg1 = (o1 & 0xffu) != 0;
    const us2 sh0 = __builtin_bit_cast(us2, fg0 ? 0u : 0x00080008u);
    const us2 sh1 = __builtin_bit_cast(us2, fg1 ? 0u : 0x00080008u);
    us2 b0 = __builtin_bit_cast(us2, 0xffffffffu), b1 = b0;
    #pragma unroll
    for (int j = 0; j < 9; ++j) {
      us2 wj = __builtin_bit_cast(us2, w[j]);
      us2 m0 = (wj >> sh0) & (us2)0x00ff;
      us2 m1 = (wj >> sh1) & (us2)0x00ff;
      b0 = __builtin_elementwise_min(b0, (us2)(m0 * m0 + __builtin_bit_cast(us2, KP0[j])));
      b1 = __builtin_elementwise_min(b1, (us2)(m1 * m1 + __builtin_bit_cast(us2, KP1[j])));
    }
    u32 best0 = min((u32)b0[0], (u32)b0[1]);
    u32 best1 = min((u32)b1[0], (u32)b1[1]);

    if (__any(max(uo0, uo1) > 8)) {            // rare exact fallback, dy 8..32
      const int c0r = 2 * (E0 + k2), c1r = c0r + 1;
      const int s0b = fg0 ? 0 : 8, s1b = fg1 ? 0 : 8;
      #pragma unroll 1
      for (int dy = 8; dy <= HALO; ++dy) {
        int q = dy * dy;
        {
          int rd = c0r + dy, ru = c0r - dy;
          u32 dd = colp[rd >> 1], du = colp[ru >> 1];
          int ud = (int)((dd >> (((rd & 1) * 16) + s0b)) & 0xffu);
          int uu = (int)((du >> (((ru & 1) * 16) + s0b)) & 0xffu);
          best0 = min(best0, (u32)(ud * ud + q));
          best0 = min(best0, (u32)(uu * uu + q));
        }
        {
          int rd = c1r + dy, ru = c1r - dy;
          u32 dd = colp[rd >> 1], du = colp[ru >> 1];
          int ud = (int)((dd >> (((rd & 1) * 16) + s1b)) & 0xffu);
          int uu = (int)((du >> (((ru & 1) * 16) + s1b)) & 0xffu);
          best1 = min(best1, (u32)(ud * ud + q));
          best1 = min(best1, (u32)(uu * uu + q));
        }
      }
    }

    // epilogue rows 2*k2 and 2*k2+1
    {
      float D = sqrtf((float)best0);
      float v = ip0[(size_t)(2 * k2) * WW];
      float p = 1.0f / (1.0f + __expf(-v));
      float pD = p * D;
      aP += p;
      aS += fg0 ? -pD : pD;
      if (fg0) { aTP += p; aC += 1; }
      aM = max(aM, best0);
    }
    {
      float D = sqrtf((float)best1);
      float v = ip0[(size_t)(2 * k2 + 1) * WW];
      float p = 1.0f / (1.0f + __expf(-v));
      float pD = p * D;
      aP += p;
      aS += fg1 ? -pD : pD;
      if (fg1) { aTP += p; aC += 1; }
      aM = max(aM, best1);
    }

    if (k2 < 7) {                              // slide window (reg rotation)
      #pragma unroll
      for (int j = 0; j < 8; ++j) w[j] = w[j + 1];
      w[8] = colp[E0 + k2 + 5];
    }
  }

  // wave reduce
  #pragma unroll
  for (int off = 32; off >= 1; off >>= 1) {
    aP  += __shfl_xor(aP, off);
    aTP += __shfl_xor(aTP, off);
    aS  += __shfl_xor(aS, off);
    aC  += __shfl_xor(aC, off);
    aM = max(aM, (u32)__shfl_xor((int)aM, off));
  }
  __shared__ float rP[4], rTP[4], rS[4];
  __shared__ u32 rM[4]; __shared__ int rC[4];
  if (lane == 0) { rP[wv] = aP; rTP[wv] = aTP; rS[wv] = aS; rM[wv] = aM; rC[wv] = aC; }
  __syncthreads();
  if (tid == 0) {
    int part = (b * 8 + xt) * 8 + cg;
    partP[part]  = rP[0] + rP[1] + rP[2] + rP[3];
    partTP[part] = rTP[0] + rTP[1] + rTP[2] + rTP[3];
    partS[part]  = rS[0] + rS[1] + rS[2] + rS[3];
    partM[part]  = max(max(rM[0], rM[1]), max(rM[2], rM[3]));
    partT[part]  = rC[0] + rC[1] + rC[2] + rC[3];
  }
}

// ---------------- Kernel C: finalize scalar loss -----------------------------
__global__ void __launch_bounds__(256) k_final(const float* __restrict__ partS,
                                               const u32* __restrict__ partM,
                                               const float* __restrict__ partP,
                                               const float* __restrict__ partTP,
                                               const int* __restrict__ partT,
                                               float* __restrict__ out) {
  const int t = threadIdx.x;
  const int img = t >> 4, j = t & 15;          // 16 threads per image
  float s = 0.f, p = 0.f, tp = 0.f; int tc = 0; u32 m2 = 0;
  #pragma unroll
  for (int q = 0; q < 4; ++q) {
    int e = img * 64 + j + q * 16;
    s += partS[e]; p += partP[e]; tp += partTP[e]; tc += partT[e];
    m2 = max(m2, partM[e]);
  }
  #pragma unroll
  for (int off = 8; off >= 1; off >>= 1) {
    s  += __shfl_xor(s, off);
    p  += __shfl_xor(p, off);
    tp += __shfl_xor(tp, off);
    tc += __shfl_xor(tc, off);
    m2 = max(m2, (u32)__shfl_xor((int)m2, off));
  }
  __shared__ float shC[16], shP[16], shTP[16]; __shared__ int shT[16];
  if (j == 0) {
    float bmax = sqrtf((float)m2);
    shC[img] = (tc > 0) ? (s / (bmax + 1e-8f)) : 0.0f;   // anypos guard
    shP[img] = p; shTP[img] = tp; shT[img] = tc;
  }
  __syncthreads();
  if (t == 0) {
    float sumP = 0.f, TP = 0.f, sumT = 0.f, bl = 0.f;
    for (int i = 0; i < 16; ++i) { sumP += shP[i]; TP += shTP[i]; sumT += (float)shT[i]; bl += shC[i]; }
    float FP = sumP - TP, FN = sumT - TP;
    float tv = (TP + 1.0f) / (TP + 0.3f * FP + 0.7f * FN + 1.0f);
    float ft = powf(1.0f - tv, 1.33f);
    float dice = (2.0f * TP + 1.0f) / (sumP + sumT + 1.0f);
    float dl = 1.0f - dice;
    float blm = bl / (float)NPIX;
    if (isnan(ft)) ft = 0.0f;
    if (isnan(dl)) dl = 0.0f;
    if (isnan(blm)) blm = 0.0f;
    out[0] = 0.5f * ft + 0.3f * dl + 0.2f * blm;
  }
}

extern "C" void kernel_launch(void* const* d_in, const int* in_sizes, int n_in,
                              void* d_out, int out_size, void* d_ws, size_t ws_size,
                              hipStream_t stream) {
  const float* inp = (const float*)d_in[0];
  const int* tg = (const int*)d_in[1];
  float* out = (float*)d_out;
  char* ws = (char*)d_ws;
  char* d1b = (char*)(ws + D1_OFF);
  float* partS  = (float*)(ws + PART_OFF);
  u32*   partM  = (u32*)(ws + PART_OFF + 4096);
  float* partP  = (float*)(ws + PART_OFF + 8192);
  float* partTP = (float*)(ws + PART_OFF + 12288);
  int*   partT  = (int*)(ws + PART_OFF + 16384);

  hipLaunchKernelGGL(k_rows, dim3(BB * HH / 4), dim3(256), 0, stream, tg, d1b);
  hipLaunchKernelGGL(k_env, dim3(WW / 64, HH / XT, BB), dim3(256), 0, stream,
                     d1b, inp, partS, partM, partP, partTP, partT);
  hipLaunchKernelGGL(k_final, dim3(1), dim3(256), 0, stream,
                     partS, partM, partP, partTP, partT, out);
}

// Round 7
// 26.718 us; speedup vs baseline: 1.1843x; 1.1843x over previous
//
#include <hip/hip_runtime.h>
#include <cstdint>

typedef unsigned short u16;
typedef unsigned int u32;
typedef unsigned short us2 __attribute__((ext_vector_type(2)));

constexpr int BB = 16, HH = 512, WW = 512;
constexpr int NPIX = BB * HH * WW;          // 4,194,304

// workspace layout (bytes)
constexpr size_t D1_OFF   = 0;                    // s8 signed d1 (cap 127), 4 MiB
constexpr size_t PART_OFF = (size_t)NPIX;
constexpr int NPART = 16 * 16 * 8;                // 2048 partial slots

// envelope tiling
constexpr int HALO  = 16;                 // vertical halo (deep search cap)
constexpr int XT    = 32;                 // output rows per block
constexpr int TROWS = XT + 2 * HALO;      // 64 tile rows
constexpr int CDW   = TROWS / 2 + 1;      // 33 dwords per padded LDS column

// ---------------- Kernel A: per-row 1D distances (single boundary scan) ------
// d1 = distance to nearest opposite-value pixel in the row (= distance to the
// nearest run boundary), capped at 127. v = t ? +d1 : -d1 stored as s8.
__global__ void __launch_bounds__(256) k_rows(const int* __restrict__ tg,
                                              char* __restrict__ d1b) {
  const int lane = threadIdx.x & 63;
  const int wv   = threadIdx.x >> 6;
  const int row  = blockIdx.x * 4 + wv;        // b*512 + h, 8192 rows
  const int c0   = lane * 8;
  const int* rp  = tg + (size_t)row * WW;
  int4 va = *(const int4*)(rp + c0);
  int4 vb = *(const int4*)(rp + c0 + 4);
  int t[8] = {va.x, va.y, va.z, va.w, vb.x, vb.y, vb.z, vb.w};
  int tprev0 = __shfl_up(t[7], 1);   // lane0 value unused (i==0 case)
  int tnext7 = __shfl_down(t[0], 1); // lane63 value unused (i==511 case)

  // left boundary positions, inclusive prefix max
  int lm[8]; int m = -2048;
  #pragma unroll
  for (int k = 0; k < 8; ++k) {
    int i = c0 + k;
    int tp = (k == 0) ? tprev0 : t[k - 1];
    int c = (i > 0 && t[k] != tp) ? i : -2048;
    m = max(m, c); lm[k] = m;
  }
  int X = m;
  #pragma unroll
  for (int off = 1; off < 64; off <<= 1) {
    int y = __shfl_up(X, off);
    if (lane >= off) X = max(X, y);
  }
  int E = __shfl_up(X, 1); if (lane == 0) E = -2048;

  // right boundary positions, inclusive suffix min
  int sm[8]; m = 2559;
  #pragma unroll
  for (int k = 7; k >= 0; --k) {
    int i = c0 + k;
    int tn = (k == 7) ? tnext7 : t[k + 1];
    int c = (i < 511 && t[k] != tn) ? i : 2559;
    m = min(m, c); sm[k] = m;
  }
  int X2 = m;
  #pragma unroll
  for (int off = 1; off < 64; off <<= 1) {
    int y = __shfl_down(X2, off);
    if (lane + off < 64) X2 = min(X2, y);
  }
  int E2 = __shfl_down(X2, 1); if (lane == 63) E2 = 2559;

  u32 lo = 0, hi = 0;
  #pragma unroll
  for (int k = 0; k < 8; ++k) {
    int i = c0 + k;
    int L = max(lm[k], E), R = min(sm[k], E2);
    int d1 = min(min(i - L + 1, R - i + 1), 127);
    int v = t[k] ? d1 : -d1;
    u32 b8 = (u32)(v & 0xff);
    if (k < 4) lo |= b8 << (8 * k); else hi |= b8 << (8 * (k - 4));
  }
  uint2 o = make_uint2(lo, hi);
  ((uint2*)d1b)[(size_t)row * (WW / 8) + lane] = o;
}

// ------------- Kernel B: column lower-envelope + all reductions --------------
// Per-row body, parity P = (tile row) & 1 (compile-time). Window of 8
// consecutive dwords (16 rows) covers dy 1..7 both sides; dy^2 pairs are
// compile-time packed constants; candidates evaluated with packed u16 math.
// Sentinel 127 pads OOB rows (no image-boundary clamping anywhere).
template <int P>
__device__ __forceinline__ void row_body(
    int e, const u32* __restrict__ pc, const u32* __restrict__ nc,
    const float* __restrict__ ip,
    float& aP, float& aTP, float& aS, u32& aM, int& aC) {
  constexpr u16 KL[2][8] = {{64, 36, 16, 4, 0, 4, 16, 36},
                            {49, 25,  9, 1, 1, 9, 25, 49}};
  constexpr u16 KH[2][8] = {{49, 25,  9, 1, 1, 9, 25, 49},
                            {36, 16,  4, 0, 4, 16, 36, 64}};
  const u32 pd = pc[e], nd = nc[e];
  const int vp = (P == 0) ? (int)(pd & 0xffffu) : (int)(pd >> 16);
  const int vn = (P == 0) ? (int)(nd & 0xffffu) : (int)(nd >> 16);
  const bool fg = vp > 0;
  const int uo = max(vp, vn);                  // own-class 1D distance (one is 0)
  const u32* cb = fg ? pc : nc;                // search own-class tile
  const us2* cb2 = (const us2*)cb;
  const int s = e + P - 4;                     // window dwords s..s+7
  us2 bestpk = __builtin_bit_cast(us2, 0xffffffffu);
  #pragma unroll
  for (int i = 0; i < 8; ++i) {
    us2 w = cb2[s + i];
    us2 k = __builtin_bit_cast(us2, (u32)KL[P][i] | ((u32)KH[P][i] << 16));
    us2 cnd = (us2)(w * w + k);
    bestpk = __builtin_elementwise_min(bestpk, cnd);
  }
  u32 best = min((u32)(uo * uo), (u32)min((u32)bestpk[0], (u32)bestpk[1]));
  if (__any(uo > 8)) {                         // rare exact fallback, dy 8..HALO
    const int c = 2 * e + P;
    #pragma unroll 1
    for (int dy = 8; dy <= HALO; ++dy) {
      int rd = c + dy, ru = c - dy;
      u32 dd = cb[rd >> 1], du = cb[ru >> 1];
      int ud = (int)((dd >> ((rd & 1) * 16)) & 0xffffu);
      int uu = (int)((du >> ((ru & 1) * 16)) & 0xffffu);
      int q = dy * dy;
      best = min(best, (u32)(ud * ud + q));
      best = min(best, (u32)(uu * uu + q));
    }
  }
  float D = sqrtf((float)best);                // = posdis+negdis at this pixel
  float v = *ip;
  float p = 1.0f / (1.0f + __expf(-v));
  aP += p;
  if (fg) { aTP += p; aC += 1; aS -= p * D; } else { aS += p * D; }
  aM = max(aM, best);
}

__global__ void __launch_bounds__(256, 8) k_env(const char* __restrict__ d1b,
                                                const float* __restrict__ inp,
                                                float* __restrict__ partS,
                                                u32* __restrict__ partM,
                                                float* __restrict__ partP,
                                                float* __restrict__ partTP,
                                                int* __restrict__ partT) {
  __shared__ u32 posT[64 * CDW];               // column-major u16, 2 rows/dword
  __shared__ u32 negT[64 * CDW];
  const int tid = threadIdx.x;
  const int cg = blockIdx.x, xt = blockIdx.y, b = blockIdx.z;
  const int w0 = cg * 64, x0 = xt * XT;

  // transposed two-class staging: 256 units = (row-pair r2 0..31) x (c8 0..7)
  {
    int r2 = tid >> 3, c8 = tid & 7;
    int g0 = x0 - HALO + 2 * r2;
    const char* base = d1b + ((size_t)(b * HH)) * WW + w0 + c8 * 8;
    uint2 A = make_uint2(0, 0), Bv = make_uint2(0, 0);
    bool ok0 = (unsigned)g0 < (unsigned)HH;
    bool ok1 = (unsigned)(g0 + 1) < (unsigned)HH;
    if (ok0) A  = *(const uint2*)(base + (size_t)g0 * WW);
    if (ok1) Bv = *(const uint2*)(base + (size_t)(g0 + 1) * WW);
    u32 aw[2] = {A.x, A.y}, bw[2] = {Bv.x, Bv.y};
    #pragma unroll
    for (int j = 0; j < 8; ++j) {
      int sa = ((int)(aw[j >> 2] << ((3 - (j & 3)) * 8))) >> 24;  // sext byte
      int sb = ((int)(bw[j >> 2] << ((3 - (j & 3)) * 8))) >> 24;
      int vpa = ok0 ? max(sa, 0) : 127, vna = ok0 ? max(-sa, 0) : 127;
      int vpb = ok1 ? max(sb, 0) : 127, vnb = ok1 ? max(-sb, 0) : 127;
      int col = c8 * 8 + j;
      posT[col * CDW + r2] = (u32)vpa | ((u32)vpb << 16);
      negT[col * CDW + r2] = (u32)vna | ((u32)vnb << 16);
    }
  }
  __syncthreads();

  const int wv = tid >> 6, lane = tid & 63;
  const u32* pc = posT + lane * CDW;
  const u32* nc = negT + lane * CDW;
  const float* ip0 = inp + ((size_t)(b * HH + x0 + wv * 8)) * WW + w0 + lane;
  float aP = 0.f, aTP = 0.f, aS = 0.f;
  u32 aM = 0; int aC = 0;

  #pragma unroll 1
  for (int k2 = 0; k2 < 4; ++k2) {
    const int e = (HALO + wv * 8) / 2 + k2;    // own row-pair dword index
    row_body<0>(e, pc, nc, ip0 + (size_t)(2 * k2) * WW,     aP, aTP, aS, aM, aC);
    row_body<1>(e, pc, nc, ip0 + (size_t)(2 * k2 + 1) * WW, aP, aTP, aS, aM, aC);
  }

  // wave reduce
  #pragma unroll
  for (int off = 32; off >= 1; off >>= 1) {
    aP  += __shfl_xor(aP, off);
    aTP += __shfl_xor(aTP, off);
    aS  += __shfl_xor(aS, off);
    aC  += __shfl_xor(aC, off);
    aM = max(aM, (u32)__shfl_xor((int)aM, off));
  }
  __shared__ float rP[4], rTP[4], rS[4];
  __shared__ u32 rM[4]; __shared__ int rC[4];
  if (lane == 0) { rP[wv] = aP; rTP[wv] = aTP; rS[wv] = aS; rM[wv] = aM; rC[wv] = aC; }
  __syncthreads();
  if (tid == 0) {
    int part = (b * 16 + xt) * 8 + cg;
    partP[part]  = rP[0] + rP[1] + rP[2] + rP[3];
    partTP[part] = rTP[0] + rTP[1] + rTP[2] + rTP[3];
    partS[part]  = rS[0] + rS[1] + rS[2] + rS[3];
    partM[part]  = max(max(rM[0], rM[1]), max(rM[2], rM[3]));
    partT[part]  = rC[0] + rC[1] + rC[2] + rC[3];
  }
}

// ---------------- Kernel C: finalize scalar loss -----------------------------
__global__ void __launch_bounds__(256) k_final(const float* __restrict__ partS,
                                               const u32* __restrict__ partM,
                                               const float* __restrict__ partP,
                                               const float* __restrict__ partTP,
                                               const int* __restrict__ partT,
                                               float* __restrict__ out) {
  const int t = threadIdx.x;
  const int img = t >> 4, j = t & 15;          // 16 threads per image
  float s = 0.f, p = 0.f, tp = 0.f; int tc = 0; u32 m2 = 0;
  #pragma unroll
  for (int q = 0; q < 8; ++q) {
    int e = img * 128 + j + q * 16;
    s += partS[e]; p += partP[e]; tp += partTP[e]; tc += partT[e];
    m2 = max(m2, partM[e]);
  }
  #pragma unroll
  for (int off = 8; off >= 1; off >>= 1) {
    s  += __shfl_xor(s, off);
    p  += __shfl_xor(p, off);
    tp += __shfl_xor(tp, off);
    tc += __shfl_xor(tc, off);
    m2 = max(m2, (u32)__shfl_xor((int)m2, off));
  }
  __shared__ float shC[16], shP[16], shTP[16]; __shared__ int shT[16];
  if (j == 0) {
    float bmax = sqrtf((float)m2);
    shC[img] = (tc > 0) ? (s / (bmax + 1e-8f)) : 0.0f;   // anypos guard
    shP[img] = p; shTP[img] = tp; shT[img] = tc;
  }
  __syncthreads();
  if (t == 0) {
    float sumP = 0.f, TP = 0.f, sumT = 0.f, bl = 0.f;
    for (int i = 0; i < 16; ++i) { sumP += shP[i]; TP += shTP[i]; sumT += (float)shT[i]; bl += shC[i]; }
    float FP = sumP - TP, FN = sumT - TP;
    float tv = (TP + 1.0f) / (TP + 0.3f * FP + 0.7f * FN + 1.0f);
    float ft = powf(1.0f - tv, 1.33f);
    float dice = (2.0f * TP + 1.0f) / (sumP + sumT + 1.0f);
    float dl = 1.0f - dice;
    float blm = bl / (float)NPIX;
    if (isnan(ft)) ft = 0.0f;
    if (isnan(dl)) dl = 0.0f;
    if (isnan(blm)) blm = 0.0f;
    out[0] = 0.5f * ft + 0.3f * dl + 0.2f * blm;
  }
}

extern "C" void kernel_launch(void* const* d_in, const int* in_sizes, int n_in,
                              void* d_out, int out_size, void* d_ws, size_t ws_size,
                              hipStream_t stream) {
  const float* inp = (const float*)d_in[0];
  const int* tg = (const int*)d_in[1];
  float* out = (float*)d_out;
  char* ws = (char*)d_ws;
  char* d1b = (char*)(ws + D1_OFF);
  float* partS  = (float*)(ws + PART_OFF);
  u32*   partM  = (u32*)(ws + PART_OFF + 8192);
  float* partP  = (float*)(ws + PART_OFF + 16384);
  float* partTP = (float*)(ws + PART_OFF + 24576);
  int*   partT  = (int*)(ws + PART_OFF + 32768);

  hipLaunchKernelGGL(k_rows, dim3(BB * HH / 4), dim3(256), 0, stream, tg, d1b);
  hipLaunchKernelGGL(k_env, dim3(WW / 64, HH / XT, BB), dim3(256), 0, stream,
                     d1b, inp, partS, partM, partP, partTP, partT);
  hipLaunchKernelGGL(k_final, dim3(1), dim3(256), 0, stream,
                     partS, partM, partP, partTP, partT, out);
}